// Round 2
// baseline (322.547 us; speedup 1.0000x reference)
//
#include <hip/hip_runtime.h>

#define TAL 0.07f
constexpr int N = 8192;
constexpr int D = 1024;

typedef __bf16 bf16x8 __attribute__((ext_vector_type(8)));
typedef float f32x4 __attribute__((ext_vector_type(4)));

static __device__ __forceinline__ ushort f2bf(float x) {
    union { float f; uint32_t u; } c; c.f = x;
    uint32_t u = c.u;
    uint32_t r = (u + 0x7FFFu + ((u >> 16) & 1u)) >> 16;   // RNE
    return (ushort)r;
}

// Kernel 1: fp32 -> bf16 convert + per-row scale a_i = 1/sqrt(TAL * ||f_i||^2)
__global__ __launch_bounds__(256) void prep_kernel(const float* __restrict__ F,
                                                   ushort* __restrict__ Fb,
                                                   float* __restrict__ ascale) {
    int row = blockIdx.x;
    int t = threadIdx.x;
    const float4* src = (const float4*)(F + (size_t)row * D);
    float4 v = src[t];
    ushort4 o;
    o.x = f2bf(v.x); o.y = f2bf(v.y); o.z = f2bf(v.z); o.w = f2bf(v.w);
    ((ushort4*)(Fb + (size_t)row * D))[t] = o;
    float local = v.x*v.x + v.y*v.y + v.z*v.z + v.w*v.w;
    #pragma unroll
    for (int off = 32; off; off >>= 1) local += __shfl_xor(local, off);
    __shared__ float red[4];
    if ((t & 63) == 0) red[t >> 6] = local;
    __syncthreads();
    if (t == 0) {
        float ss = red[0] + red[1] + red[2] + red[3];
        ascale[row] = rsqrtf(TAL * ss);
    }
}

// Kernel 2: label histogram (labels in [1,80))
__global__ void hist_kernel(const int* __restrict__ lab, int* __restrict__ hist) {
    int i = blockIdx.x * blockDim.x + threadIdx.x;
    if (i < N) atomicAdd(&hist[lab[i]], 1);
}

// Kernel 3: tiled bf16 MFMA Gram matrix with fused column reductions.
// G[i][j] = <f_i, f_j>; ex = G * a_i * a_j.
// Accumulate per column j: sumE[j] += exp(ex - 1/TAL); sumP[j] += (lab_i==lab_j) ? ex : 0.
// NOTE: ex and pos are symmetric, so col-sum == row-sum -> transpose-immune.
#define BM 128
#define BN 128
#define BK 32
#define LDT 40   // padded LDS row stride (bf16 elems): 80B -> ~2-way bank conflicts (free)

__global__ __launch_bounds__(256) void gemm_kernel(const ushort* __restrict__ Fb,
                                                   const float* __restrict__ ascale,
                                                   const int* __restrict__ lab,
                                                   float* __restrict__ gSumE,
                                                   float* __restrict__ gSumP) {
    __shared__ ushort sA[BM][LDT];
    __shared__ ushort sB[BN][LDT];
    __shared__ float rScale[BM], cScale[BN];
    __shared__ int rLab[BM], cLab[BN];

    int bi = blockIdx.x & 63;
    int bj = blockIdx.x >> 6;
    int I0 = bi * BM, J0 = bj * BN;
    int t = threadIdx.x;
    int lane = t & 63, w = t >> 6;
    int wr = w >> 1, wc = w & 1;

    if (t < 128) { rScale[t] = ascale[I0 + t]; rLab[t] = lab[I0 + t]; }
    else { int u = t - 128; cScale[u] = ascale[J0 + u]; cLab[u] = lab[J0 + u]; }

    f32x4 acc[4][4];
    #pragma unroll
    for (int m = 0; m < 4; ++m)
        #pragma unroll
        for (int n = 0; n < 4; ++n)
            acc[m][n] = {0.f, 0.f, 0.f, 0.f};

    int sr = t >> 2;          // 0..63 staging row
    int sc = (t & 3) * 8;     // 0,8,16,24 staging col (bf16 elems)
    int kb = (lane >> 4) * 8; // fragment k-offset

    for (int k0 = 0; k0 < D; k0 += BK) {
        __syncthreads();
        #pragma unroll
        for (int h = 0; h < 2; ++h) {
            int row = h * 64 + sr;
            uint4 va = *(const uint4*)(Fb + (size_t)(I0 + row) * D + k0 + sc);
            *(uint4*)(&sA[row][sc]) = va;
            uint4 vb = *(const uint4*)(Fb + (size_t)(J0 + row) * D + k0 + sc);
            *(uint4*)(&sB[row][sc]) = vb;
        }
        __syncthreads();
        bf16x8 af[4], bfr[4];
        #pragma unroll
        for (int m = 0; m < 4; ++m)
            af[m] = *(const bf16x8*)(&sA[wr * 64 + m * 16 + (lane & 15)][kb]);
        #pragma unroll
        for (int n = 0; n < 4; ++n)
            bfr[n] = *(const bf16x8*)(&sB[wc * 64 + n * 16 + (lane & 15)][kb]);
        #pragma unroll
        for (int m = 0; m < 4; ++m)
            #pragma unroll
            for (int n = 0; n < 4; ++n)
                acc[m][n] = __builtin_amdgcn_mfma_f32_16x16x32_bf16(af[m], bfr[n], acc[m][n], 0, 0, 0);
    }

    // Epilogue: ex = acc * a_i * a_j; fused per-column reductions.
    // C/D layout (m89-verified): col = lane&15, row = (lane>>4)*4 + reg.
    float rs[16]; int rl[16];
    int rbase = wr * 64 + (lane >> 4) * 4;
    #pragma unroll
    for (int m = 0; m < 4; ++m)
        #pragma unroll
        for (int r = 0; r < 4; ++r) {
            rs[m * 4 + r] = rScale[rbase + m * 16 + r];
            rl[m * 4 + r] = rLab[rbase + m * 16 + r];
        }

    const float CSH = 1.0f / TAL;
    #pragma unroll
    for (int n = 0; n < 4; ++n) {
        int jl = wc * 64 + n * 16 + (lane & 15);
        float aj = cScale[jl];
        int lj = cLab[jl];
        float se = 0.f, sp = 0.f;
        #pragma unroll
        for (int m = 0; m < 4; ++m)
            #pragma unroll
            for (int r = 0; r < 4; ++r) {
                float ex = acc[m][n][r] * rs[m * 4 + r] * aj;
                se += __expf(ex - CSH);
                sp += (rl[m * 4 + r] == lj) ? ex : 0.f;
            }
        se += __shfl_xor(se, 16); se += __shfl_xor(se, 32);
        sp += __shfl_xor(sp, 16); sp += __shfl_xor(sp, 32);
        if (lane < 16) {
            atomicAdd(&gSumE[J0 + jl], se);
            atomicAdd(&gSumP[J0 + jl], sp);
        }
    }
}

// Kernel 4: loss = (1/n) * sum_j [ 1/TAL + log(sumE[j]) - sumP[j]/n_pos[j] ]
__global__ __launch_bounds__(256) void finalize_kernel(const float* __restrict__ gSumE,
                                                       const float* __restrict__ gSumP,
                                                       const int* __restrict__ lab,
                                                       const int* __restrict__ hist,
                                                       float* __restrict__ out) {
    int t = threadIdx.x;
    const float CSH = 1.0f / TAL;
    float local = 0.f;
    for (int j = t; j < N; j += 256) {
        float np = (float)hist[lab[j]];
        local += CSH + logf(gSumE[j]) - gSumP[j] / np;
    }
    #pragma unroll
    for (int off = 32; off; off >>= 1) local += __shfl_xor(local, off);
    __shared__ float red[4];
    if ((t & 63) == 0) red[t >> 6] = local;
    __syncthreads();
    if (t == 0) out[0] = (red[0] + red[1] + red[2] + red[3]) / (float)N;
}

extern "C" void kernel_launch(void* const* d_in, const int* in_sizes, int n_in,
                              void* d_out, int out_size, void* d_ws, size_t ws_size,
                              hipStream_t stream) {
    const float* F = (const float*)d_in[0];
    const int* lab = (const int*)d_in[1];
    float* out = (float*)d_out;
    char* ws = (char*)d_ws;

    const size_t FB_BYTES = (size_t)N * D * 2;        // 16 MiB
    ushort* Fb    = (ushort*)ws;
    float* ascale = (float*)(ws + FB_BYTES);
    float* gSumE  = (float*)(ws + FB_BYTES + 32768);
    float* gSumP  = (float*)(ws + FB_BYTES + 65536);
    int*   hist   = (int*)  (ws + FB_BYTES + 98304);

    // zero accumulators (harness poisons ws with 0xAA before every launch)
    hipMemsetAsync(ws + FB_BYTES + 32768, 0, 65536 + 512, stream);

    prep_kernel<<<N, 256, 0, stream>>>(F, Fb, ascale);
    hist_kernel<<<N / 256, 256, 0, stream>>>(lab, hist);
    gemm_kernel<<<(N / BM) * (N / BN), 256, 0, stream>>>(Fb, ascale, lab, gSumE, gSumP);
    finalize_kernel<<<1, 256, 0, stream>>>(gSumE, gSumP, lab, hist, out);
}

// Round 5
// 283.148 us; speedup vs baseline: 1.1391x; 1.1391x over previous
//
#include <hip/hip_runtime.h>

#define TAL 0.07f
constexpr int N = 8192;
constexpr int D = 1024;
constexpr int NB = 64;                     // N / BM
constexpr int NTILES = NB * (NB + 1) / 2;  // lower-triangle incl. diagonal = 2080

typedef __bf16 bf16x8 __attribute__((ext_vector_type(8)));
typedef float f32x4 __attribute__((ext_vector_type(4)));

#define AS1 __attribute__((address_space(1)))
#define AS3 __attribute__((address_space(3)))

static __device__ __forceinline__ ushort f2bf(float x) {
    union { float f; uint32_t u; } c; c.f = x;
    uint32_t u = c.u;
    uint32_t r = (u + 0x7FFFu + ((u >> 16) & 1u)) >> 16;   // RNE
    return (ushort)r;
}

// Kernel 1: fp32 -> bf16 convert + per-row scale a_i = 1/sqrt(TAL*||f_i||^2).
// One wave per row: no __syncthreads, no LDS.
__global__ __launch_bounds__(256) void prep_kernel(const float* __restrict__ F,
                                                   ushort* __restrict__ Fb,
                                                   float* __restrict__ ascale) {
    int row = blockIdx.x * 4 + (threadIdx.x >> 6);
    int lane = threadIdx.x & 63;
    const float4* src = (const float4*)(F + (size_t)row * D);
    ushort4* dst = (ushort4*)(Fb + (size_t)row * D);
    float local = 0.f;
    #pragma unroll
    for (int it = 0; it < 4; ++it) {
        float4 v = src[it * 64 + lane];
        ushort4 o;
        o.x = f2bf(v.x); o.y = f2bf(v.y); o.z = f2bf(v.z); o.w = f2bf(v.w);
        dst[it * 64 + lane] = o;
        local += v.x*v.x + v.y*v.y + v.z*v.z + v.w*v.w;
    }
    #pragma unroll
    for (int off = 32; off; off >>= 1) local += __shfl_xor(local, off);
    if (lane == 0) ascale[row] = rsqrtf(TAL * local);
}

// Kernel 2: label histogram (labels in [1,80))
__global__ void hist_kernel(const int* __restrict__ lab, int* __restrict__ hist) {
    int i = blockIdx.x * blockDim.x + threadIdx.x;
    if (i < N) atomicAdd(&hist[lab[i]], 1);
}

// Kernel 3: symmetric-tiled bf16 MFMA Gram matrix with fused reductions.
// Only lower-triangle tiles (bi >= bj); off-diagonal tiles also scatter their
// row sums to the I-block accumulators (ex and pos are symmetric).
// Staging: global_load_lds width=16, linear LDS [128][32] bf16 (no swizzle
// on either side -- rule #21).
#define BM 128
#define BN 128
#define BK 32

__global__ __launch_bounds__(256) void gemm_kernel(const ushort* __restrict__ Fb,
                                                   const float* __restrict__ ascale,
                                                   const int* __restrict__ lab,
                                                   float* __restrict__ gSumE,
                                                   float* __restrict__ gSumP) {
    __shared__ ushort sA[BM * BK];   // linear: row*32 + col
    __shared__ ushort sB[BN * BK];
    __shared__ float rScale[BM], cScale[BN];
    __shared__ int rLab[BM], cLab[BN];

    // triangular decode: b = bi*(bi+1)/2 + bj, bj <= bi
    int b = blockIdx.x;
    int bi = (int)((sqrtf(8.f * (float)b + 1.f) - 1.f) * 0.5f);
    while ((bi + 1) * (bi + 2) / 2 <= b) ++bi;
    while (bi * (bi + 1) / 2 > b) --bi;
    int bj = b - bi * (bi + 1) / 2;
    bool offdiag = (bi != bj);

    int I0 = bi * BM, J0 = bj * BN;
    int t = threadIdx.x;
    int lane = t & 63, w = t >> 6;
    int wr = w >> 1, wc = w & 1;

    if (t < 128) { rScale[t] = ascale[I0 + t]; rLab[t] = lab[I0 + t]; }
    else { int u = t - 128; cScale[u] = ascale[J0 + u]; cLab[u] = lab[J0 + u]; }

    f32x4 acc[4][4];
    #pragma unroll
    for (int m = 0; m < 4; ++m)
        #pragma unroll
        for (int n = 0; n < 4; ++n)
            acc[m][n] = {0.f, 0.f, 0.f, 0.f};

    // global_load_lds staging geometry: wave w, instr q in {0,1} covers LDS
    // bytes [(w*2+q)*1024, +1024): row = (w*2+q)*16 + lane/4, colelem = (lane&3)*8.
    int rA0 = (w * 2 + 0) * 16 + (lane >> 2);
    int rA1 = (w * 2 + 1) * 16 + (lane >> 2);
    int ce  = (lane & 3) * 8;
    const ushort* srcA0 = Fb + (size_t)(I0 + rA0) * D + ce;
    const ushort* srcA1 = Fb + (size_t)(I0 + rA1) * D + ce;
    const ushort* srcB0 = Fb + (size_t)(J0 + rA0) * D + ce;
    const ushort* srcB1 = Fb + (size_t)(J0 + rA1) * D + ce;
    ushort* dstA0 = sA + (w * 2 + 0) * 512;   // 512 ushort = 1024 B (wave-uniform)
    ushort* dstA1 = sA + (w * 2 + 1) * 512;
    ushort* dstB0 = sB + (w * 2 + 0) * 512;
    ushort* dstB1 = sB + (w * 2 + 1) * 512;

    int kb = (lane >> 4) * 8;   // fragment k-offset (bf16 elems)
    int fr = lane & 15;         // fragment row/col within 16

    for (int k0 = 0; k0 < D; k0 += BK) {
        __syncthreads();   // previous iteration's reads complete before overwrite
        __builtin_amdgcn_global_load_lds((const AS1 void*)(srcA0 + k0), (AS3 void*)dstA0, 16, 0, 0);
        __builtin_amdgcn_global_load_lds((const AS1 void*)(srcA1 + k0), (AS3 void*)dstA1, 16, 0, 0);
        __builtin_amdgcn_global_load_lds((const AS1 void*)(srcB0 + k0), (AS3 void*)dstB0, 16, 0, 0);
        __builtin_amdgcn_global_load_lds((const AS1 void*)(srcB1 + k0), (AS3 void*)dstB1, 16, 0, 0);
        asm volatile("s_waitcnt vmcnt(0)" ::: "memory");
        __syncthreads();   // all waves' stages visible

        bf16x8 af[4], bfr[4];
        #pragma unroll
        for (int m = 0; m < 4; ++m)
            af[m] = *(const bf16x8*)(sA + (wr * 64 + m * 16 + fr) * BK + kb);
        #pragma unroll
        for (int n = 0; n < 4; ++n)
            bfr[n] = *(const bf16x8*)(sB + (wc * 64 + n * 16 + fr) * BK + kb);
        #pragma unroll
        for (int m = 0; m < 4; ++m)
            #pragma unroll
            for (int n = 0; n < 4; ++n)
                acc[m][n] = __builtin_amdgcn_mfma_f32_16x16x32_bf16(af[m], bfr[n], acc[m][n], 0, 0, 0);
    }

    // Epilogue. C/D layout (m89-verified): col = lane&15, row = (lane>>4)*4 + reg.
    float rs[16]; int rl[16];
    int rbase = wr * 64 + (lane >> 4) * 4;
    #pragma unroll
    for (int m = 0; m < 4; ++m)
        #pragma unroll
        for (int r = 0; r < 4; ++r) {
            rs[m * 4 + r] = rScale[rbase + m * 16 + r];
            rl[m * 4 + r] = rLab[rbase + m * 16 + r];
        }

    const float CSH = 1.0f / TAL;
    float colE[4], colP[4], rowE[16], rowP[16];
    #pragma unroll
    for (int n = 0; n < 4; ++n) { colE[n] = 0.f; colP[n] = 0.f; }
    #pragma unroll
    for (int q = 0; q < 16; ++q) { rowE[q] = 0.f; rowP[q] = 0.f; }

    #pragma unroll
    for (int n = 0; n < 4; ++n) {
        int jl = wc * 64 + n * 16 + fr;
        float aj = cScale[jl];
        int lj = cLab[jl];
        #pragma unroll
        for (int m = 0; m < 4; ++m)
            #pragma unroll
            for (int r = 0; r < 4; ++r) {
                float ex = acc[m][n][r] * rs[m * 4 + r] * aj;
                float e = __expf(ex - CSH);
                float p = (rl[m * 4 + r] == lj) ? ex : 0.f;
                colE[n] += e; colP[n] += p;
                rowE[m * 4 + r] += e; rowP[m * 4 + r] += p;
            }
    }

    // column contributions (always): reduce across the 4 row-groups per wave
    #pragma unroll
    for (int n = 0; n < 4; ++n) {
        float se = colE[n], sp = colP[n];
        se += __shfl_xor(se, 16); se += __shfl_xor(se, 32);
        sp += __shfl_xor(sp, 16); sp += __shfl_xor(sp, 32);
        if (lane < 16) {
            int jl = wc * 64 + n * 16 + lane;
            atomicAdd(&gSumE[J0 + jl], se);
            atomicAdd(&gSumP[J0 + jl], sp);
        }
    }

    // row contributions (off-diagonal only): reduce across the 16 col-lanes
    if (offdiag) {
        #pragma unroll
        for (int q = 0; q < 16; ++q) {
            float se = rowE[q], sp = rowP[q];
            se += __shfl_xor(se, 1); se += __shfl_xor(se, 2);
            se += __shfl_xor(se, 4); se += __shfl_xor(se, 8);
            sp += __shfl_xor(sp, 1); sp += __shfl_xor(sp, 2);
            sp += __shfl_xor(sp, 4); sp += __shfl_xor(sp, 8);
            if ((lane & 15) == 0) {
                int row = rbase + (q >> 2) * 16 + (q & 3);
                atomicAdd(&gSumE[I0 + row], se);
                atomicAdd(&gSumP[I0 + row], sp);
            }
        }
    }
}

// Kernel 4: loss = (1/n) * sum_j [ 1/TAL + log(sumE[j]) - sumP[j]/n_pos[j] ]
__global__ __launch_bounds__(256) void finalize_kernel(const float* __restrict__ gSumE,
                                                       const float* __restrict__ gSumP,
                                                       const int* __restrict__ lab,
                                                       const int* __restrict__ hist,
                                                       float* __restrict__ out) {
    int t = threadIdx.x;
    const float CSH = 1.0f / TAL;
    float local = 0.f;
    for (int j = t; j < N; j += 256) {
        float np = (float)hist[lab[j]];
        local += CSH + logf(gSumE[j]) - gSumP[j] / np;
    }
    #pragma unroll
    for (int off = 32; off; off >>= 1) local += __shfl_xor(local, off);
    __shared__ float red[4];
    if ((t & 63) == 0) red[t >> 6] = local;
    __syncthreads();
    if (t == 0) out[0] = (red[0] + red[1] + red[2] + red[3]) / (float)N;
}

extern "C" void kernel_launch(void* const* d_in, const int* in_sizes, int n_in,
                              void* d_out, int out_size, void* d_ws, size_t ws_size,
                              hipStream_t stream) {
    const float* F = (const float*)d_in[0];
    const int* lab = (const int*)d_in[1];
    float* out = (float*)d_out;
    char* ws = (char*)d_ws;

    const size_t FB_BYTES = (size_t)N * D * 2;        // 16 MiB
    ushort* Fb    = (ushort*)ws;
    float* ascale = (float*)(ws + FB_BYTES);
    float* gSumE  = (float*)(ws + FB_BYTES + 32768);
    float* gSumP  = (float*)(ws + FB_BYTES + 65536);
    int*   hist   = (int*)  (ws + FB_BYTES + 98304);

    // zero accumulators (harness poisons ws with 0xAA before every launch)
    hipMemsetAsync(ws + FB_BYTES + 32768, 0, 65536 + 512, stream);

    prep_kernel<<<N / 4, 256, 0, stream>>>(F, Fb, ascale);
    hist_kernel<<<N / 256, 256, 0, stream>>>(lab, hist);
    gemm_kernel<<<NTILES, 256, 0, stream>>>(Fb, ascale, lab, gSumE, gSumP);
    finalize_kernel<<<1, 256, 0, stream>>>(gSumE, gSumP, lab, hist, out);
}

// Round 6
// 242.268 us; speedup vs baseline: 1.3314x; 1.1687x over previous
//
#include <hip/hip_runtime.h>

#define TAL 0.07f
constexpr int N = 8192;
constexpr int D = 1024;
constexpr int NB = 64;                     // N / BM
constexpr int NTILES = NB * (NB + 1) / 2;  // 2080 = 8 * 260 (exact XCD split)
constexpr int TPX = NTILES / 8;            // 260 tiles per XCD chunk

typedef __bf16 bf16x8 __attribute__((ext_vector_type(8)));
typedef float f32x4 __attribute__((ext_vector_type(4)));

#define AS1 __attribute__((address_space(1)))
#define AS3 __attribute__((address_space(3)))

static __device__ __forceinline__ ushort f2bf(float x) {
    union { float f; uint32_t u; } c; c.f = x;
    uint32_t u = c.u;
    uint32_t r = (u + 0x7FFFu + ((u >> 16) & 1u)) >> 16;   // RNE
    return (ushort)r;
}

// Kernel 1: fp32 -> bf16 convert + per-row scale a_i = 1/sqrt(TAL*||f_i||^2).
__global__ __launch_bounds__(256) void prep_kernel(const float* __restrict__ F,
                                                   ushort* __restrict__ Fb,
                                                   float* __restrict__ ascale) {
    int row = blockIdx.x * 4 + (threadIdx.x >> 6);
    int lane = threadIdx.x & 63;
    const float4* src = (const float4*)(F + (size_t)row * D);
    ushort4* dst = (ushort4*)(Fb + (size_t)row * D);
    float local = 0.f;
    #pragma unroll
    for (int it = 0; it < 4; ++it) {
        float4 v = src[it * 64 + lane];
        ushort4 o;
        o.x = f2bf(v.x); o.y = f2bf(v.y); o.z = f2bf(v.z); o.w = f2bf(v.w);
        dst[it * 64 + lane] = o;
        local += v.x*v.x + v.y*v.y + v.z*v.z + v.w*v.w;
    }
    #pragma unroll
    for (int off = 32; off; off >>= 1) local += __shfl_xor(local, off);
    if (lane == 0) ascale[row] = rsqrtf(TAL * local);
}

// Kernel 2: label histogram (labels in [1,80))
__global__ void hist_kernel(const int* __restrict__ lab, int* __restrict__ hist) {
    int i = blockIdx.x * blockDim.x + threadIdx.x;
    if (i < N) atomicAdd(&hist[lab[i]], 1);
}

// Kernel 3: symmetric-tiled bf16 MFMA Gram matrix, T3-minimum 2-phase
// double-buffered global_load_lds staging, XCD-chunked tile mapping.
#define BM 128
#define BN 128
#define BK 32
#define TILE (BM * BK)   // ushorts per LDS tile buffer
#define NSTEP (D / BK)   // 32

__global__ __launch_bounds__(256, 4) void gemm_kernel(const ushort* __restrict__ Fb,
                                                      const float* __restrict__ ascale,
                                                      const int* __restrict__ lab,
                                                      float* __restrict__ gSumE,
                                                      float* __restrict__ gSumP) {
    __shared__ ushort sA[2][TILE];   // linear: row*32 + col
    __shared__ ushort sB[2][TILE];
    __shared__ float rScale[BM], cScale[BN];
    __shared__ int rLab[BM], cLab[BN];

    // XCD-chunked bijective remap: HW assigns block k to XCD k%8; give each
    // XCD a contiguous band of the triangle for L2 panel reuse.
    int k = blockIdx.x;
    int b = (k & 7) * TPX + (k >> 3);

    // triangular decode: b = bi*(bi+1)/2 + bj, bj <= bi
    int bi = (int)((sqrtf(8.f * (float)b + 1.f) - 1.f) * 0.5f);
    while ((bi + 1) * (bi + 2) / 2 <= b) ++bi;
    while (bi * (bi + 1) / 2 > b) --bi;
    int bj = b - bi * (bi + 1) / 2;
    bool offdiag = (bi != bj);

    int I0 = bi * BM, J0 = bj * BN;
    int t = threadIdx.x;
    int lane = t & 63, w = t >> 6;
    int wr = w >> 1, wc = w & 1;

    if (t < 128) { rScale[t] = ascale[I0 + t]; rLab[t] = lab[I0 + t]; }
    else { int u = t - 128; cScale[u] = ascale[J0 + u]; cLab[u] = lab[J0 + u]; }

    f32x4 acc[4][4];
    #pragma unroll
    for (int m = 0; m < 4; ++m)
        #pragma unroll
        for (int n = 0; n < 4; ++n)
            acc[m][n] = {0.f, 0.f, 0.f, 0.f};

    // Staging geometry (rule #21: linear LDS dest, matching per-lane global src):
    // wave w, instr q in {0,1}: LDS bytes [(w*2+q)*1024, +1024) of the tile,
    // i.e. row (w*2+q)*16 + lane/4, col (lane&3)*8 bf16.
    int r0 = (w * 2 + 0) * 16 + (lane >> 2);
    int r1 = (w * 2 + 1) * 16 + (lane >> 2);
    int ce = (lane & 3) * 8;
    const ushort* srcA0 = Fb + (size_t)(I0 + r0) * D + ce;
    const ushort* srcA1 = Fb + (size_t)(I0 + r1) * D + ce;
    const ushort* srcB0 = Fb + (size_t)(J0 + r0) * D + ce;
    const ushort* srcB1 = Fb + (size_t)(J0 + r1) * D + ce;
    ushort* sAf = &sA[0][0];
    ushort* sBf = &sB[0][0];
    int d0 = (w * 2 + 0) * 512;   // wave-uniform LDS dest (ushort units)
    int d1 = (w * 2 + 1) * 512;

#define STAGE(c, koff) do {                                                                              \
    __builtin_amdgcn_global_load_lds((const AS1 void*)(srcA0 + (koff)), (AS3 void*)(sAf + (c)*TILE + d0), 16, 0, 0); \
    __builtin_amdgcn_global_load_lds((const AS1 void*)(srcA1 + (koff)), (AS3 void*)(sAf + (c)*TILE + d1), 16, 0, 0); \
    __builtin_amdgcn_global_load_lds((const AS1 void*)(srcB0 + (koff)), (AS3 void*)(sBf + (c)*TILE + d0), 16, 0, 0); \
    __builtin_amdgcn_global_load_lds((const AS1 void*)(srcB1 + (koff)), (AS3 void*)(sBf + (c)*TILE + d1), 16, 0, 0); \
} while (0)

    int kb = (lane >> 4) * 8;   // fragment k-offset (bf16 elems)
    int fr = lane & 15;         // fragment row/col within 16

    STAGE(0, 0);
    __syncthreads();            // staging of step 0 complete (+ scale/lab stores)

    int cur = 0;
    for (int step = 0; step < NSTEP; ++step) {
        if (step + 1 < NSTEP) STAGE(cur ^ 1, (step + 1) * BK);   // prefetch next tile

        const ushort* a = sAf + cur * TILE;
        const ushort* bb = sBf + cur * TILE;
        bf16x8 af[4], bfr[4];
        #pragma unroll
        for (int m = 0; m < 4; ++m)
            af[m] = *(const bf16x8*)(a + (wr * 64 + m * 16 + fr) * BK + kb);
        #pragma unroll
        for (int n = 0; n < 4; ++n)
            bfr[n] = *(const bf16x8*)(bb + (wc * 64 + n * 16 + fr) * BK + kb);
        #pragma unroll
        for (int m = 0; m < 4; ++m)
            #pragma unroll
            for (int n = 0; n < 4; ++n)
                acc[m][n] = __builtin_amdgcn_mfma_f32_16x16x32_bf16(af[m], bfr[n], acc[m][n], 0, 0, 0);

        if (step + 1 < NSTEP) __syncthreads();  // drains this wave's prefetch vmcnt
                                                // + lgkm (reads of buf[cur] done) -> safe flip
        cur ^= 1;
    }

    // Epilogue. C/D layout (m89-verified): col = lane&15, row = (lane>>4)*4 + reg.
    float rs[16]; int rl[16];
    int rbase = wr * 64 + (lane >> 4) * 4;
    #pragma unroll
    for (int m = 0; m < 4; ++m)
        #pragma unroll
        for (int r = 0; r < 4; ++r) {
            rs[m * 4 + r] = rScale[rbase + m * 16 + r];
            rl[m * 4 + r] = rLab[rbase + m * 16 + r];
        }

    const float CSH = 1.0f / TAL;
    float colE[4], colP[4], rowE[16], rowP[16];
    #pragma unroll
    for (int n = 0; n < 4; ++n) { colE[n] = 0.f; colP[n] = 0.f; }
    #pragma unroll
    for (int q = 0; q < 16; ++q) { rowE[q] = 0.f; rowP[q] = 0.f; }

    #pragma unroll
    for (int n = 0; n < 4; ++n) {
        int jl = wc * 64 + n * 16 + fr;
        float aj = cScale[jl];
        int lj = cLab[jl];
        #pragma unroll
        for (int m = 0; m < 4; ++m)
            #pragma unroll
            for (int r = 0; r < 4; ++r) {
                float ex = acc[m][n][r] * rs[m * 4 + r] * aj;
                float e = __expf(ex - CSH);
                float p = (rl[m * 4 + r] == lj) ? ex : 0.f;
                colE[n] += e; colP[n] += p;
                rowE[m * 4 + r] += e; rowP[m * 4 + r] += p;
            }
    }

    // column contributions (always): reduce across the 4 row-groups per wave
    #pragma unroll
    for (int n = 0; n < 4; ++n) {
        float se = colE[n], sp = colP[n];
        se += __shfl_xor(se, 16); se += __shfl_xor(se, 32);
        sp += __shfl_xor(sp, 16); sp += __shfl_xor(sp, 32);
        if (lane < 16) {
            int jl = wc * 64 + n * 16 + lane;
            atomicAdd(&gSumE[J0 + jl], se);
            atomicAdd(&gSumP[J0 + jl], sp);
        }
    }

    // row contributions (off-diagonal only): reduce across the 16 col-lanes
    if (offdiag) {
        #pragma unroll
        for (int q = 0; q < 16; ++q) {
            float se = rowE[q], sp = rowP[q];
            se += __shfl_xor(se, 1); se += __shfl_xor(se, 2);
            se += __shfl_xor(se, 4); se += __shfl_xor(se, 8);
            sp += __shfl_xor(sp, 1); sp += __shfl_xor(sp, 2);
            sp += __shfl_xor(sp, 4); sp += __shfl_xor(sp, 8);
            if ((lane & 15) == 0) {
                int row = rbase + (q >> 2) * 16 + (q & 3);
                atomicAdd(&gSumE[I0 + row], se);
                atomicAdd(&gSumP[I0 + row], sp);
            }
        }
    }
}

// Kernel 4: loss = (1/n) * sum_j [ 1/TAL + log(sumE[j]) - sumP[j]/n_pos[j] ]
__global__ __launch_bounds__(256) void finalize_kernel(const float* __restrict__ gSumE,
                                                       const float* __restrict__ gSumP,
                                                       const int* __restrict__ lab,
                                                       const int* __restrict__ hist,
                                                       float* __restrict__ out) {
    int t = threadIdx.x;
    const float CSH = 1.0f / TAL;
    float local = 0.f;
    for (int j = t; j < N; j += 256) {
        float np = (float)hist[lab[j]];
        local += CSH + logf(gSumE[j]) - gSumP[j] / np;
    }
    #pragma unroll
    for (int off = 32; off; off >>= 1) local += __shfl_xor(local, off);
    __shared__ float red[4];
    if ((t & 63) == 0) red[t >> 6] = local;
    __syncthreads();
    if (t == 0) out[0] = (red[0] + red[1] + red[2] + red[3]) / (float)N;
}

extern "C" void kernel_launch(void* const* d_in, const int* in_sizes, int n_in,
                              void* d_out, int out_size, void* d_ws, size_t ws_size,
                              hipStream_t stream) {
    const float* F = (const float*)d_in[0];
    const int* lab = (const int*)d_in[1];
    float* out = (float*)d_out;
    char* ws = (char*)d_ws;

    const size_t FB_BYTES = (size_t)N * D * 2;        // 16 MiB
    ushort* Fb    = (ushort*)ws;
    float* ascale = (float*)(ws + FB_BYTES);
    float* gSumE  = (float*)(ws + FB_BYTES + 32768);
    float* gSumP  = (float*)(ws + FB_BYTES + 65536);
    int*   hist   = (int*)  (ws + FB_BYTES + 98304);

    // zero accumulators (harness poisons ws with 0xAA before every launch)
    hipMemsetAsync(ws + FB_BYTES + 32768, 0, 65536 + 512, stream);

    prep_kernel<<<N / 4, 256, 0, stream>>>(F, Fb, ascale);
    hist_kernel<<<N / 256, 256, 0, stream>>>(lab, hist);
    gemm_kernel<<<NTILES, 256, 0, stream>>>(Fb, ascale, lab, gSumE, gSumP);
    finalize_kernel<<<1, 256, 0, stream>>>(gSumE, gSumP, lab, hist, out);
}